// Round 1
// baseline (842.155 us; speedup 1.0000x reference)
//
#include <hip/hip_runtime.h>

// SpatialGraphConv: N=100000 nodes, CIN=COUT=32, T=12, E=1600000 edges.
// out[n,d,t] = b[d] + sum_c W[c,d] * agg[n,c,t],
// agg[n,:,:] = dinv[n]^2 * x[n,:,:] + sum_{e: dst=n} dinv[src]*w_e*dinv[n] * x[src,:,:]
// deg[n] = 1.0 (self loop) + sum_{e: dst=n} edge_attr[e];  dinv = rsqrt(deg)

constexpr int CIN  = 32;
constexpr int TT   = 12;
constexpr int COUT = 32;
constexpr int FPN  = CIN * TT;   // 384 floats per node row
constexpr int SROW = 388;        // padded LDS row (388 % 32 == 4 -> bank spread)

// ---------------- CSR build ----------------

__global__ void k_count_deg(const int* __restrict__ ei, const float* __restrict__ ea,
                            int* __restrict__ cnt, float* __restrict__ deg, int E) {
    int e = blockIdx.x * 256 + threadIdx.x;
    if (e < E) {
        int d = ei[E + e];
        atomicAdd(&cnt[d], 1);
        atomicAdd(&deg[d], ea[e]);
    }
}

__global__ void k_dinv(float* __restrict__ deg, int n) {
    int i = blockIdx.x * 256 + threadIdx.x;
    if (i < n) {
        float s = deg[i] + 1.0f;               // self-loop weight 1.0
        deg[i] = (s > 0.0f) ? rsqrtf(s) : 0.0f;
    }
}

__global__ void k_scan1(const int* __restrict__ cnt, int* __restrict__ rp,
                        int* __restrict__ bsums, int n) {
    __shared__ int sh[256];
    int t = threadIdx.x;
    int i = blockIdx.x * 256 + t;
    int v = (i < n) ? cnt[i] : 0;
    sh[t] = v;
    __syncthreads();
    for (int off = 1; off < 256; off <<= 1) {
        int add = (t >= off) ? sh[t - off] : 0;
        __syncthreads();
        sh[t] += add;
        __syncthreads();
    }
    if (i < n) rp[i] = sh[t] - v;              // exclusive within block
    if (t == 255) bsums[blockIdx.x] = sh[255];
}

__global__ void k_scan2(int* __restrict__ bsums, int nb) {   // one block, 1024 threads
    __shared__ int sh[1024];
    int t = threadIdx.x;
    int v = (t < nb) ? bsums[t] : 0;
    sh[t] = v;
    __syncthreads();
    for (int off = 1; off < 1024; off <<= 1) {
        int add = (t >= off) ? sh[t - off] : 0;
        __syncthreads();
        sh[t] += add;
        __syncthreads();
    }
    if (t < nb) bsums[t] = sh[t] - v;          // exclusive
}

__global__ void k_scan3(int* __restrict__ rp, const int* __restrict__ bsums,
                        int* __restrict__ cursor, int n) {
    int i = blockIdx.x * 256 + threadIdx.x;
    if (i < n) {
        int r = rp[i] + bsums[blockIdx.x];
        rp[i] = r;
        cursor[i] = r;
    }
}

__global__ void k_fill(const int* __restrict__ ei, const float* __restrict__ ea,
                       const float* __restrict__ dinv, int* __restrict__ cursor,
                       int2* __restrict__ csr, int E) {
    int e = blockIdx.x * 256 + threadIdx.x;
    if (e < E) {
        int s = ei[e];
        int d = ei[E + e];
        int slot = atomicAdd(&cursor[d], 1);
        float nm = dinv[s] * ea[e] * dinv[d];
        csr[slot] = make_int2(s, __float_as_int(nm));
    }
}

// ---------------- main fused kernel ----------------
// block = 256 threads (4 waves), handles 16 nodes.
// Phase 1: each wave aggregates 4 nodes (register acc, float2 x3) -> LDS.
// Phase 2: threads 0..191 = (node_local, t); 32-wide W matmul, W via uniform loads.
// Phase 3: write back through LDS with coalesced float4 stores.

__launch_bounds__(256)
__global__ void k_main(const float* __restrict__ x, const float* __restrict__ W,
                       const float* __restrict__ b, const float* __restrict__ dinv,
                       const int* __restrict__ rp, const int* __restrict__ cnt,
                       const int2* __restrict__ csr, float* __restrict__ out, int n) {
    __shared__ float sAgg[16 * SROW];
    const int tid  = threadIdx.x;
    const int wave = tid >> 6;
    const int lane = tid & 63;
    const int base = blockIdx.x * 16;

    // ---- Phase 1: aggregation ----
    for (int q = 0; q < 4; ++q) {
        int nl = wave * 4 + q;
        int nd = base + nl;
        if (nd < n) {
            float sn = dinv[nd];
            sn = sn * sn;                       // self-loop norm
            const float2* xr = (const float2*)(x + (size_t)nd * FPN);
            float2 a0 = xr[lane], a1 = xr[lane + 64], a2 = xr[lane + 128];
            a0.x *= sn; a0.y *= sn; a1.x *= sn; a1.y *= sn; a2.x *= sn; a2.y *= sn;
            int st = rp[nd];
            int c  = cnt[nd];
            for (int j = 0; j < c; ++j) {
                int2 p = csr[st + j];
                int   s  = p.x;
                float nm = __int_as_float(p.y);
                const float2* xs = (const float2*)(x + (size_t)s * FPN);
                float2 v0 = xs[lane], v1 = xs[lane + 64], v2 = xs[lane + 128];
                a0.x += nm * v0.x; a0.y += nm * v0.y;
                a1.x += nm * v1.x; a1.y += nm * v1.y;
                a2.x += nm * v2.x; a2.y += nm * v2.y;
            }
            float* ag = sAgg + nl * SROW;
            ((float2*)ag)[lane]       = a0;
            ((float2*)ag)[lane + 64]  = a1;
            ((float2*)ag)[lane + 128] = a2;
        }
    }
    __syncthreads();

    // ---- Phase 2: per-(node,t) W transform ----
    int nl = tid / 12;
    int t  = tid - nl * 12;
    bool act = (tid < 192) && (base + nl < n);
    float acc[COUT];
    if (act) {
        #pragma unroll
        for (int d = 0; d < COUT; ++d) acc[d] = b[d];
        const float* ag = sAgg + nl * SROW + t;
        #pragma unroll
        for (int c = 0; c < CIN; ++c) {
            float xv = ag[c * TT];
            #pragma unroll
            for (int d = 0; d < COUT; ++d) acc[d] += xv * W[c * COUT + d];
        }
    }
    __syncthreads();
    if (act) {
        float* og = sAgg + nl * SROW;          // reuse LDS as output staging
        #pragma unroll
        for (int d = 0; d < COUT; ++d) og[d * TT + t] = acc[d];
    }
    __syncthreads();

    // ---- Phase 3: coalesced store ----
    for (int m = tid; m < 16 * (FPN / 4); m += 256) {   // 16 * 96 float4
        int nl2 = m / 96;
        int off = m - nl2 * 96;
        int nd  = base + nl2;
        if (nd < n) {
            float4 v = *((const float4*)(sAgg + nl2 * SROW) + off);
            *((float4*)(out + (size_t)nd * FPN) + off) = v;
        }
    }
}

// ---------------- launch ----------------

extern "C" void kernel_launch(void* const* d_in, const int* in_sizes, int n_in,
                              void* d_out, int out_size, void* d_ws, size_t ws_size,
                              hipStream_t stream) {
    const float* x  = (const float*)d_in[0];
    const int*   ei = (const int*)d_in[1];
    const float* ea = (const float*)d_in[2];
    const float* W  = (const float*)d_in[3];
    const float* b  = (const float*)d_in[4];
    float* out = (float*)d_out;

    const int E = in_sizes[2];            // 1,600,000
    const int N = in_sizes[0] / FPN;      // 100,000

    // workspace layout (8B-aligned first)
    char* w = (char*)d_ws;
    int2*  csr    = (int2*)w;                               w += (size_t)E * sizeof(int2);
    float* deg    = (float*)w;                              w += (size_t)N * sizeof(float);
    int*   cnt    = (int*)w;                                w += (size_t)N * sizeof(int);
    int*   rowp   = (int*)w;                                w += (size_t)N * sizeof(int);
    int*   cursor = (int*)w;                                w += (size_t)N * sizeof(int);
    int*   bsums  = (int*)w;

    const int NB = (N + 255) / 256;       // 391 blocks (<=1024 for scan2)
    const int EB = (E + 255) / 256;

    hipMemsetAsync(deg, 0, (size_t)N * sizeof(float), stream);
    hipMemsetAsync(cnt, 0, (size_t)N * sizeof(int), stream);

    k_count_deg<<<EB, 256, 0, stream>>>(ei, ea, cnt, deg, E);
    k_dinv<<<NB, 256, 0, stream>>>(deg, N);
    k_scan1<<<NB, 256, 0, stream>>>(cnt, rowp, bsums, N);
    k_scan2<<<1, 1024, 0, stream>>>(bsums, NB);
    k_scan3<<<NB, 256, 0, stream>>>(rowp, bsums, cursor, N);
    k_fill<<<EB, 256, 0, stream>>>(ei, ea, deg /*=dinv*/, cursor, csr, E);

    const int MB = (N + 15) / 16;         // 6250 blocks
    k_main<<<MB, 256, 0, stream>>>(x, W, b, deg /*=dinv*/, rowp, cnt, csr, out, N);
}

// Round 3
// 812.351 us; speedup vs baseline: 1.0367x; 1.0367x over previous
//
#include <hip/hip_runtime.h>

// SpatialGraphConv: N=100000 nodes, CIN=COUT=32, T=12, E=1600000 edges.
// out[n,d,t] = b[d] + sum_c W[c,d] * agg[n,c,t],
// agg[n,:,:] = dinv[n]^2 * x[n,:,:] + sum_{e: dst=n} dinv[src]*w_e*dinv[n] * x[src,:,:]
// deg[n] = 1.0 (self loop) + sum_{e: dst=n} edge_attr[e];  dinv = rsqrt(deg)

constexpr int CIN  = 32;
constexpr int TT   = 12;
constexpr int COUT = 32;
constexpr int FPN  = CIN * TT;   // 384 floats per node row
constexpr int SROW = 388;        // padded LDS row

typedef float f4 __attribute__((ext_vector_type(4)));   // native vec for nontemporal

// ---------------- CSR build ----------------

__global__ void k_count_deg(const int* __restrict__ ei, const float* __restrict__ ea,
                            int* __restrict__ cnt, float* __restrict__ deg, int E) {
    int e = blockIdx.x * 256 + threadIdx.x;
    if (e < E) {
        int d = ei[E + e];
        atomicAdd(&cnt[d], 1);
        atomicAdd(&deg[d], ea[e]);
    }
}

// block scan of cnt + fused dinv computation (independent elementwise op)
__global__ void k_scan1(const int* __restrict__ cnt, int* __restrict__ rp,
                        int* __restrict__ bsums, float* __restrict__ deg, int n) {
    __shared__ int sh[256];
    int t = threadIdx.x;
    int i = blockIdx.x * 256 + t;
    if (i < n) {
        float s = deg[i] + 1.0f;               // self-loop weight 1.0
        deg[i] = (s > 0.0f) ? rsqrtf(s) : 0.0f;
    }
    int v = (i < n) ? cnt[i] : 0;
    sh[t] = v;
    __syncthreads();
    for (int off = 1; off < 256; off <<= 1) {
        int add = (t >= off) ? sh[t - off] : 0;
        __syncthreads();
        sh[t] += add;
        __syncthreads();
    }
    if (i < n) rp[i] = sh[t] - v;              // exclusive within block
    if (t == 255) bsums[blockIdx.x] = sh[255];
}

__global__ void k_scan2(int* __restrict__ bsums, int nb) {   // one block, 1024 threads
    __shared__ int sh[1024];
    int t = threadIdx.x;
    int v = (t < nb) ? bsums[t] : 0;
    sh[t] = v;
    __syncthreads();
    for (int off = 1; off < 1024; off <<= 1) {
        int add = (t >= off) ? sh[t - off] : 0;
        __syncthreads();
        sh[t] += add;
        __syncthreads();
    }
    if (t < nb) bsums[t] = sh[t] - v;          // exclusive
}

__global__ void k_scan3(int* __restrict__ rp, const int* __restrict__ bsums,
                        int* __restrict__ cursor, int n) {
    int i = blockIdx.x * 256 + threadIdx.x;
    if (i < n) {
        int r = rp[i] + bsums[blockIdx.x];
        rp[i] = r;
        cursor[i] = r;
    }
}

__global__ void k_fill(const int* __restrict__ ei, const float* __restrict__ ea,
                       const float* __restrict__ dinv, int* __restrict__ cursor,
                       long long* __restrict__ csr, int E) {
    int e = blockIdx.x * 256 + threadIdx.x;
    if (e < E) {
        int s = ei[e];
        int d = ei[E + e];
        int slot = atomicAdd(&cursor[d], 1);
        float nm = dinv[s] * ea[e] * dinv[d];
        long long packed = ((long long)__float_as_int(nm) << 32) | (unsigned int)s;
        __builtin_nontemporal_store(packed, csr + slot);   // random scatter: bypass cache
    }
}

// ---------------- main fused kernel ----------------
// block = 256 threads (4 waves), handles 16 nodes.
// Phase 1: each wave aggregates 4 nodes; edge loop unrolled x4 for MLP
//          (12 independent float2 gathers in flight -> latency-hiding).
// Phase 2: threads 0..191 = (node_local, t); 32-wide W matmul (W uniform loads).
// Phase 3: coalesced non-temporal float4 stores.

__launch_bounds__(256)
__global__ void k_main(const float* __restrict__ x, const float* __restrict__ W,
                       const float* __restrict__ b, const float* __restrict__ dinv,
                       const int* __restrict__ rp, const int* __restrict__ cnt,
                       const int2* __restrict__ csr, float* __restrict__ out, int n) {
    __shared__ float sAgg[16 * SROW];
    const int tid  = threadIdx.x;
    const int wave = tid >> 6;
    const int lane = tid & 63;
    const int base = blockIdx.x * 16;

    // ---- Phase 1: aggregation ----
    for (int q = 0; q < 4; ++q) {
        int nl = wave * 4 + q;
        int nd = base + nl;
        if (nd < n) {
            float sn = dinv[nd];
            sn = sn * sn;                       // self-loop norm
            const float2* xr = (const float2*)(x + (size_t)nd * FPN);
            float2 a0 = xr[lane], a1 = xr[lane + 64], a2 = xr[lane + 128];
            a0.x *= sn; a0.y *= sn; a1.x *= sn; a1.y *= sn; a2.x *= sn; a2.y *= sn;
            int st = rp[nd];
            int c  = cnt[nd];
            int j  = 0;
            for (; j + 4 <= c; j += 4) {
                int2 p0 = csr[st + j + 0];
                int2 p1 = csr[st + j + 1];
                int2 p2 = csr[st + j + 2];
                int2 p3 = csr[st + j + 3];
                const float2* s0 = (const float2*)(x + (size_t)p0.x * FPN);
                const float2* s1 = (const float2*)(x + (size_t)p1.x * FPN);
                const float2* s2 = (const float2*)(x + (size_t)p2.x * FPN);
                const float2* s3 = (const float2*)(x + (size_t)p3.x * FPN);
                // 12 independent gathers issued before any use
                float2 v00 = s0[lane], v01 = s0[lane + 64], v02 = s0[lane + 128];
                float2 v10 = s1[lane], v11 = s1[lane + 64], v12 = s1[lane + 128];
                float2 v20 = s2[lane], v21 = s2[lane + 64], v22 = s2[lane + 128];
                float2 v30 = s3[lane], v31 = s3[lane + 64], v32 = s3[lane + 128];
                float n0 = __int_as_float(p0.y), n1 = __int_as_float(p1.y);
                float n2 = __int_as_float(p2.y), n3 = __int_as_float(p3.y);
                a0.x = fmaf(n0, v00.x, a0.x); a0.y = fmaf(n0, v00.y, a0.y);
                a1.x = fmaf(n0, v01.x, a1.x); a1.y = fmaf(n0, v01.y, a1.y);
                a2.x = fmaf(n0, v02.x, a2.x); a2.y = fmaf(n0, v02.y, a2.y);
                a0.x = fmaf(n1, v10.x, a0.x); a0.y = fmaf(n1, v10.y, a0.y);
                a1.x = fmaf(n1, v11.x, a1.x); a1.y = fmaf(n1, v11.y, a1.y);
                a2.x = fmaf(n1, v12.x, a2.x); a2.y = fmaf(n1, v12.y, a2.y);
                a0.x = fmaf(n2, v20.x, a0.x); a0.y = fmaf(n2, v20.y, a0.y);
                a1.x = fmaf(n2, v21.x, a1.x); a1.y = fmaf(n2, v21.y, a1.y);
                a2.x = fmaf(n2, v22.x, a2.x); a2.y = fmaf(n2, v22.y, a2.y);
                a0.x = fmaf(n3, v30.x, a0.x); a0.y = fmaf(n3, v30.y, a0.y);
                a1.x = fmaf(n3, v31.x, a1.x); a1.y = fmaf(n3, v31.y, a1.y);
                a2.x = fmaf(n3, v32.x, a2.x); a2.y = fmaf(n3, v32.y, a2.y);
            }
            for (; j < c; ++j) {
                int2 p = csr[st + j];
                int   s  = p.x;
                float nm = __int_as_float(p.y);
                const float2* xs = (const float2*)(x + (size_t)s * FPN);
                float2 v0 = xs[lane], v1 = xs[lane + 64], v2 = xs[lane + 128];
                a0.x = fmaf(nm, v0.x, a0.x); a0.y = fmaf(nm, v0.y, a0.y);
                a1.x = fmaf(nm, v1.x, a1.x); a1.y = fmaf(nm, v1.y, a1.y);
                a2.x = fmaf(nm, v2.x, a2.x); a2.y = fmaf(nm, v2.y, a2.y);
            }
            float* ag = sAgg + nl * SROW;
            ((float2*)ag)[lane]       = a0;
            ((float2*)ag)[lane + 64]  = a1;
            ((float2*)ag)[lane + 128] = a2;
        }
    }
    __syncthreads();

    // ---- Phase 2: per-(node,t) W transform ----
    int nl = tid / 12;
    int t  = tid - nl * 12;
    bool act = (tid < 192) && (base + nl < n);
    float acc[COUT];
    if (act) {
        #pragma unroll
        for (int d = 0; d < COUT; ++d) acc[d] = b[d];
        const float* ag = sAgg + nl * SROW + t;
        #pragma unroll
        for (int c = 0; c < CIN; ++c) {
            float xv = ag[c * TT];
            #pragma unroll
            for (int d = 0; d < COUT; ++d) acc[d] = fmaf(xv, W[c * COUT + d], acc[d]);
        }
    }
    __syncthreads();
    if (act) {
        float* og = sAgg + nl * SROW;          // reuse LDS as output staging
        #pragma unroll
        for (int d = 0; d < COUT; ++d) og[d * TT + t] = acc[d];
    }
    __syncthreads();

    // ---- Phase 3: coalesced non-temporal store ----
    for (int m = tid; m < 16 * (FPN / 4); m += 256) {   // 16 * 96 float4
        int nl2 = m / 96;
        int off = m - nl2 * 96;
        int nd  = base + nl2;
        if (nd < n) {
            f4 v = *((const f4*)(sAgg + nl2 * SROW) + off);
            __builtin_nontemporal_store(v, (f4*)(out + (size_t)nd * FPN) + off);
        }
    }
}

// ---------------- launch ----------------

extern "C" void kernel_launch(void* const* d_in, const int* in_sizes, int n_in,
                              void* d_out, int out_size, void* d_ws, size_t ws_size,
                              hipStream_t stream) {
    const float* x  = (const float*)d_in[0];
    const int*   ei = (const int*)d_in[1];
    const float* ea = (const float*)d_in[2];
    const float* W  = (const float*)d_in[3];
    const float* b  = (const float*)d_in[4];
    float* out = (float*)d_out;

    const int E = in_sizes[2];            // 1,600,000
    const int N = in_sizes[0] / FPN;      // 100,000

    // workspace layout (8B-aligned first)
    char* w = (char*)d_ws;
    long long* csr = (long long*)w;                         w += (size_t)E * sizeof(long long);
    float* deg    = (float*)w;                              w += (size_t)N * sizeof(float);
    int*   cnt    = (int*)w;                                w += (size_t)N * sizeof(int);
    int*   rowp   = (int*)w;                                w += (size_t)N * sizeof(int);
    int*   cursor = (int*)w;                                w += (size_t)N * sizeof(int);
    int*   bsums  = (int*)w;

    const int NB = (N + 255) / 256;       // 391 blocks (<=1024 for scan2)
    const int EB = (E + 255) / 256;

    (void)hipMemsetAsync(deg, 0, (size_t)N * sizeof(float), stream);
    (void)hipMemsetAsync(cnt, 0, (size_t)N * sizeof(int), stream);

    k_count_deg<<<EB, 256, 0, stream>>>(ei, ea, cnt, deg, E);
    k_scan1<<<NB, 256, 0, stream>>>(cnt, rowp, bsums, deg, N);
    k_scan2<<<1, 1024, 0, stream>>>(bsums, NB);
    k_scan3<<<NB, 256, 0, stream>>>(rowp, bsums, cursor, N);
    k_fill<<<EB, 256, 0, stream>>>(ei, ea, deg /*=dinv*/, cursor, csr, E);

    const int MB = (N + 15) / 16;         // 6250 blocks
    k_main<<<MB, 256, 0, stream>>>(x, W, b, deg /*=dinv*/, rowp, cnt, (const int2*)csr, out, N);
}

// Round 4
// 709.322 us; speedup vs baseline: 1.1873x; 1.1452x over previous
//
#include <hip/hip_runtime.h>

// SpatialGraphConv: N=100000 nodes, CIN=COUT=32, T=12, E=1600000 edges.
// out[n,d,t] = b[d] + sum_c W[c,d] * agg[n,c,t],
// agg[n,:,:] = dinv[n]^2 * x[n,:,:] + sum_{e: dst=n} dinv[src]*w_e*dinv[n] * x[src,:,:]
// deg[n] = 1.0 (self loop) + sum_{e: dst=n} edge_attr[e];  dinv = rsqrt(deg)

constexpr int CIN  = 32;
constexpr int TT   = 12;
constexpr int COUT = 32;
constexpr int FPN  = CIN * TT;   // 384 floats per node row
constexpr int SROW = 388;        // padded LDS row

typedef float f4 __attribute__((ext_vector_type(4)));   // native vec for nontemporal

// Packed histogram: bits [44,64) = edge count, bits [0,44) = sum(ea) in 2^-20 fixed point.
// Max sum = 1.6M * 2^20 = 2^40.6 < 2^44; count max 2^20 >> max degree. Quantization
// error on deg <= deg_max * 2^-20 ~ 1e-4 absolute -> dinv rel error ~5e-5, negligible.
constexpr unsigned long long CNT_ONE = 1ULL << 44;
constexpr unsigned long long SUM_MASK = CNT_ONE - 1;

// ---------------- pass 1: packed histogram + per-edge rank ----------------

__global__ void k_hist(const int* __restrict__ ei, const float* __restrict__ ea,
                       unsigned long long* __restrict__ hist, int* __restrict__ rank, int E) {
    int e = blockIdx.x * 256 + threadIdx.x;
    if (e < E) {
        int d = ei[E + e];
        unsigned long long q = CNT_ONE |
            (unsigned long long)(unsigned)(ea[e] * 1048576.0f);
        unsigned long long old = atomicAdd(&hist[d], q);
        rank[e] = (int)(old >> 44);          // this edge's slot within dst's row
    }
}

// ---------------- pass 2: dinv + per-block exclusive scan of counts ----------------

__global__ void k_scan1(const unsigned long long* __restrict__ hist,
                        int* __restrict__ rp, int* __restrict__ bsums,
                        float* __restrict__ dinv, int n) {
    __shared__ int sh[256];
    int t = threadIdx.x;
    int i = blockIdx.x * 256 + t;
    int v = 0;
    if (i < n) {
        unsigned long long h = hist[i];
        v = (int)(h >> 44);
        float deg = 1.0f + (float)(h & SUM_MASK) * (1.0f / 1048576.0f);
        dinv[i] = rsqrtf(deg);               // deg >= 1 always (self loop)
    }
    sh[t] = v;
    __syncthreads();
    for (int off = 1; off < 256; off <<= 1) {
        int add = (t >= off) ? sh[t - off] : 0;
        __syncthreads();
        sh[t] += add;
        __syncthreads();
    }
    if (i < n) rp[i] = sh[t] - v;            // exclusive within block
    if (t == 255) bsums[blockIdx.x] = sh[255];
}

__global__ void k_scan2(int* __restrict__ bsums, int nb) {   // one block, 1024 threads
    __shared__ int sh[1024];
    int t = threadIdx.x;
    int v = (t < nb) ? bsums[t] : 0;
    sh[t] = v;
    __syncthreads();
    for (int off = 1; off < 1024; off <<= 1) {
        int add = (t >= off) ? sh[t - off] : 0;
        __syncthreads();
        sh[t] += add;
        __syncthreads();
    }
    if (t < nb) bsums[t] = sh[t] - v;        // exclusive
}

// ---------------- pass 3: CSR fill, atomic-free (slot = rp + bsum + rank) ----------------

__global__ void k_fill(const int* __restrict__ ei, const float* __restrict__ ea,
                       const float* __restrict__ dinv, const int* __restrict__ rp,
                       const int* __restrict__ bsums, const int* __restrict__ rank,
                       long long* __restrict__ csr, int E) {
    int e = blockIdx.x * 256 + threadIdx.x;
    if (e < E) {
        int s = ei[e];
        int d = ei[E + e];
        int slot = rp[d] + bsums[d >> 8] + rank[e];
        float nm = dinv[s] * ea[e] * dinv[d];
        long long packed = ((long long)__float_as_int(nm) << 32) | (unsigned int)s;
        __builtin_nontemporal_store(packed, csr + slot);   // random scatter: bypass cache
    }
}

// ---------------- main fused kernel ----------------
// block = 256 threads (4 waves), handles 16 nodes.
// Phase 1: each wave aggregates 4 nodes; edge loop unrolled x4.
//          __launch_bounds__(256,4) -> VGPR cap 128 so the 12 gathers truly
//          stay in flight (R3's VGPR=40 showed the compiler serialized them).
// Phase 2: threads 0..191 = (node_local, t); 32-wide W matmul (W uniform loads).
// Phase 3: coalesced non-temporal float4 stores.

__launch_bounds__(256, 4)
__global__ void k_main(const float* __restrict__ x, const float* __restrict__ W,
                       const float* __restrict__ b, const float* __restrict__ dinv,
                       const int* __restrict__ rp, const int* __restrict__ bsums,
                       const unsigned long long* __restrict__ hist,
                       const int2* __restrict__ csr, float* __restrict__ out, int n) {
    __shared__ float sAgg[16 * SROW];
    const int tid  = threadIdx.x;
    const int wave = tid >> 6;
    const int lane = tid & 63;
    const int base = blockIdx.x * 16;

    // ---- Phase 1: aggregation ----
    for (int q = 0; q < 4; ++q) {
        int nl = wave * 4 + q;
        int nd = base + nl;
        if (nd < n) {
            float sn = dinv[nd];
            sn = sn * sn;                       // self-loop norm
            const float2* xr = (const float2*)(x + (size_t)nd * FPN);
            float2 a0 = xr[lane], a1 = xr[lane + 64], a2 = xr[lane + 128];
            a0.x *= sn; a0.y *= sn; a1.x *= sn; a1.y *= sn; a2.x *= sn; a2.y *= sn;
            int st = rp[nd] + bsums[nd >> 8];
            int c  = (int)(hist[nd] >> 44);
            int j  = 0;
            for (; j + 4 <= c; j += 4) {
                int2 p0 = csr[st + j + 0];
                int2 p1 = csr[st + j + 1];
                int2 p2 = csr[st + j + 2];
                int2 p3 = csr[st + j + 3];
                const float2* s0 = (const float2*)(x + (size_t)p0.x * FPN);
                const float2* s1 = (const float2*)(x + (size_t)p1.x * FPN);
                const float2* s2 = (const float2*)(x + (size_t)p2.x * FPN);
                const float2* s3 = (const float2*)(x + (size_t)p3.x * FPN);
                // 12 independent gathers issued before any use
                float2 v00 = s0[lane], v01 = s0[lane + 64], v02 = s0[lane + 128];
                float2 v10 = s1[lane], v11 = s1[lane + 64], v12 = s1[lane + 128];
                float2 v20 = s2[lane], v21 = s2[lane + 64], v22 = s2[lane + 128];
                float2 v30 = s3[lane], v31 = s3[lane + 64], v32 = s3[lane + 128];
                float n0 = __int_as_float(p0.y), n1 = __int_as_float(p1.y);
                float n2 = __int_as_float(p2.y), n3 = __int_as_float(p3.y);
                a0.x = fmaf(n0, v00.x, a0.x); a0.y = fmaf(n0, v00.y, a0.y);
                a1.x = fmaf(n0, v01.x, a1.x); a1.y = fmaf(n0, v01.y, a1.y);
                a2.x = fmaf(n0, v02.x, a2.x); a2.y = fmaf(n0, v02.y, a2.y);
                a0.x = fmaf(n1, v10.x, a0.x); a0.y = fmaf(n1, v10.y, a0.y);
                a1.x = fmaf(n1, v11.x, a1.x); a1.y = fmaf(n1, v11.y, a1.y);
                a2.x = fmaf(n1, v12.x, a2.x); a2.y = fmaf(n1, v12.y, a2.y);
                a0.x = fmaf(n2, v20.x, a0.x); a0.y = fmaf(n2, v20.y, a0.y);
                a1.x = fmaf(n2, v21.x, a1.x); a1.y = fmaf(n2, v21.y, a1.y);
                a2.x = fmaf(n2, v22.x, a2.x); a2.y = fmaf(n2, v22.y, a2.y);
                a0.x = fmaf(n3, v30.x, a0.x); a0.y = fmaf(n3, v30.y, a0.y);
                a1.x = fmaf(n3, v31.x, a1.x); a1.y = fmaf(n3, v31.y, a1.y);
                a2.x = fmaf(n3, v32.x, a2.x); a2.y = fmaf(n3, v32.y, a2.y);
            }
            for (; j < c; ++j) {
                int2 p = csr[st + j];
                int   s  = p.x;
                float nm = __int_as_float(p.y);
                const float2* xs = (const float2*)(x + (size_t)s * FPN);
                float2 v0 = xs[lane], v1 = xs[lane + 64], v2 = xs[lane + 128];
                a0.x = fmaf(nm, v0.x, a0.x); a0.y = fmaf(nm, v0.y, a0.y);
                a1.x = fmaf(nm, v1.x, a1.x); a1.y = fmaf(nm, v1.y, a1.y);
                a2.x = fmaf(nm, v2.x, a2.x); a2.y = fmaf(nm, v2.y, a2.y);
            }
            float* ag = sAgg + nl * SROW;
            ((float2*)ag)[lane]       = a0;
            ((float2*)ag)[lane + 64]  = a1;
            ((float2*)ag)[lane + 128] = a2;
        }
    }
    __syncthreads();

    // ---- Phase 2: per-(node,t) W transform ----
    int nl = tid / 12;
    int t  = tid - nl * 12;
    bool act = (tid < 192) && (base + nl < n);
    float acc[COUT];
    if (act) {
        #pragma unroll
        for (int d = 0; d < COUT; ++d) acc[d] = b[d];
        const float* ag = sAgg + nl * SROW + t;
        #pragma unroll
        for (int c = 0; c < CIN; ++c) {
            float xv = ag[c * TT];
            #pragma unroll
            for (int d = 0; d < COUT; ++d) acc[d] = fmaf(xv, W[c * COUT + d], acc[d]);
        }
    }
    __syncthreads();
    if (act) {
        float* og = sAgg + nl * SROW;          // reuse LDS as output staging
        #pragma unroll
        for (int d = 0; d < COUT; ++d) og[d * TT + t] = acc[d];
    }
    __syncthreads();

    // ---- Phase 3: coalesced non-temporal store ----
    for (int m = tid; m < 16 * (FPN / 4); m += 256) {   // 16 * 96 float4
        int nl2 = m / 96;
        int off = m - nl2 * 96;
        int nd  = base + nl2;
        if (nd < n) {
            f4 v = *((const f4*)(sAgg + nl2 * SROW) + off);
            __builtin_nontemporal_store(v, (f4*)(out + (size_t)nd * FPN) + off);
        }
    }
}

// ---------------- launch ----------------

extern "C" void kernel_launch(void* const* d_in, const int* in_sizes, int n_in,
                              void* d_out, int out_size, void* d_ws, size_t ws_size,
                              hipStream_t stream) {
    const float* x  = (const float*)d_in[0];
    const int*   ei = (const int*)d_in[1];
    const float* ea = (const float*)d_in[2];
    const float* W  = (const float*)d_in[3];
    const float* b  = (const float*)d_in[4];
    float* out = (float*)d_out;

    const int E = in_sizes[2];            // 1,600,000
    const int N = in_sizes[0] / FPN;      // 100,000

    // workspace layout (8B-aligned first)
    char* w = (char*)d_ws;
    long long*          csr  = (long long*)w;           w += (size_t)E * sizeof(long long);
    unsigned long long* hist = (unsigned long long*)w;  w += (size_t)N * sizeof(unsigned long long);
    int*   rank  = (int*)w;                             w += (size_t)E * sizeof(int);
    float* dinv  = (float*)w;                           w += (size_t)N * sizeof(float);
    int*   rowp  = (int*)w;                             w += (size_t)N * sizeof(int);
    int*   bsums = (int*)w;

    const int NB = (N + 255) / 256;       // 391 blocks (<=1024 for scan2)
    const int EB = (E + 255) / 256;

    (void)hipMemsetAsync(hist, 0, (size_t)N * sizeof(unsigned long long), stream);

    k_hist<<<EB, 256, 0, stream>>>(ei, ea, hist, rank, E);
    k_scan1<<<NB, 256, 0, stream>>>(hist, rowp, bsums, dinv, N);
    k_scan2<<<1, 1024, 0, stream>>>(bsums, NB);
    k_fill<<<EB, 256, 0, stream>>>(ei, ea, dinv, rowp, bsums, rank, csr, E);

    const int MB = (N + 15) / 16;         // 6250 blocks
    k_main<<<MB, 256, 0, stream>>>(x, W, b, dinv, rowp, bsums, hist,
                                   (const int2*)csr, out, N);
}